// Round 11
// baseline (222.953 us; speedup 1.0000x reference)
//
#include <hip/hip_runtime.h>
#include <hip/hip_bf16.h>
#include <stdint.h>

#define KDIM 512
#define OUT_F 512
#define BM 128           // rows per block
#define BNB 256          // cols per block (2 col-blocks cover 512)
#define BK 64            // k per step
#define NSTEP 8          // KDIM / BK
#define NTHREADS 512     // 8 waves, 2M x 4N

typedef __attribute__((ext_vector_type(8))) short short8;
typedef __attribute__((ext_vector_type(4))) float floatx4;

__device__ __forceinline__ ushort f2bf(float f) {
  uint32_t u = __builtin_bit_cast(uint32_t, f);
  uint32_t r = u + 0x7fffu + ((u >> 16) & 1u);   // RNE bf16
  return (ushort)(r >> 16);
}

typedef const __attribute__((address_space(1))) uint32_t* gas1_u32;
typedef __attribute__((address_space(3))) uint32_t* gas3_u32;

__device__ __forceinline__ void gload_lds16(const void* g, void* l) {
  __builtin_amdgcn_global_load_lds((gas1_u32)g, (gas3_u32)l, 16, 0, 0);
}

#define VMCNT4  asm volatile("s_waitcnt vmcnt(4)" ::: "memory")
#define VMCNT0  asm volatile("s_waitcnt vmcnt(0)" ::: "memory")
#define LGKM0   asm volatile("s_waitcnt lgkmcnt(0)" ::: "memory")
#define SBAR    __builtin_amdgcn_s_barrier()

// ---------------------------------------------------------------------------
// Prep: W_eff (512x512) bf16 as [kt(8)][ct(2)][ol(256)][k(64)], XOR swizzle
// baked in (G21: linear gload_lds dest, pre-permuted source == read perm).
// ---------------------------------------------------------------------------
__global__ void quat_prep_kernel(const float* __restrict__ wr, const float* __restrict__ wi,
                                 const float* __restrict__ wj, const float* __restrict__ wk,
                                 ushort* __restrict__ Bimg) {
  int idx = blockIdx.x * 256 + threadIdx.x;
  if (idx >= 512 * 512) return;
  int o = idx >> 9;        // output-feature index [0,512)
  int c = idx & 511;       // input-feature index [0,512)
  int og = o >> 7, oo = o & 127, cg = c >> 7, cc = c & 127;
  static const int   blkT[16] = {0,1,2,3, 1,0,3,2, 2,3,0,1, 3,2,1,0};
  static const float sgnT[16] = {1.f,-1.f,-1.f,-1.f, 1.f,1.f,1.f,-1.f,
                                 1.f,-1.f,1.f,1.f,   1.f,1.f,-1.f,1.f};
  int sel = og * 4 + cg;
  const float* Ws;
  switch (blkT[sel]) {
    case 0: Ws = wr; break;
    case 1: Ws = wi; break;
    case 2: Ws = wj; break;
    default: Ws = wk; break;
  }
  float v = sgnT[sel] * Ws[oo * 128 + cc];
  int kt = c >> 6, k = c & 63;
  int ct = o >> 8, ol = o & 255;
  int dst = ((kt * 2 + ct) * 256 + ol) * BK + (k ^ ((ol & 7) << 3));
  Bimg[dst] = f2bf(v);
}

// ---------------------------------------------------------------------------
// GEMM: out[M,512] = X[M,512] * W_eff^T (+bias)
// 128x256 block, BK=64 counted-vmcnt pipeline. LDS = A single 16KB + B dbuf
// 64KB = 80KB -> TWO blocks/CU (anti-phased: one block's memory bursts fill
// the other's barrier gaps; R7/R10's single 160KB block left the CU's memory
// path idle during drains). A 2-deep reg prefetch, never vmcnt(0) in-loop.
// ---------------------------------------------------------------------------
__global__ void __launch_bounds__(NTHREADS, 4)
quat_gemm_kernel(const float* __restrict__ X, const ushort* __restrict__ Bimg,
                 const float* __restrict__ bias, float* __restrict__ Out) {
  __shared__ __align__(16) ushort As[BM * BK];         // 16 KB (single)
  __shared__ __align__(16) ushort Bs[2][BNB * BK];     // 2 x 32 KB

  // grid: 2048 = 1024 mtiles x 2 ct; XCD swizzle, ct-pair 8 bids apart -> same XCD
  const int bid = blockIdx.x;
  const int wgid = (bid & 7) * 256 + (bid >> 3);
  const int mt = wgid >> 1;
  const int ct = wgid & 1;
  const size_t row0 = (size_t)mt * BM;

  const int tid = threadIdx.x, lane = tid & 63, wid = tid >> 6;
  const int lrow = lane & 15;
  const int lg   = lane >> 4;
  const int wm = wid >> 2, wn = wid & 3;     // 2M x 4N wave grid

  const int ar = tid >> 3;                   // A row [0,64) (+64 for 2nd half)
  const int ac = (tid & 7) * 8;              // A col [0,64) step 8

  float4 av[2][4];                           // 2-deep A prefetch (16 floats)

  auto issueA = [&](int t, int p) {
    const float* s = X + (row0 + ar) * KDIM + t * BK + ac;
    av[p][0] = *reinterpret_cast<const float4*>(s);
    av[p][1] = *reinterpret_cast<const float4*>(s + 4);
    av[p][2] = *reinterpret_cast<const float4*>(s + 64 * KDIM);
    av[p][3] = *reinterpret_cast<const float4*>(s + 64 * KDIM + 4);
  };
  auto writeA = [&](int p) {                 // cvt + swizzled ds_write (fast)
#pragma unroll
    for (int h = 0; h < 2; ++h) {
      int row = ar + h * 64;
      short8 o;
      o[0] = (short)f2bf(av[p][2*h].x); o[1] = (short)f2bf(av[p][2*h].y);
      o[2] = (short)f2bf(av[p][2*h].z); o[3] = (short)f2bf(av[p][2*h].w);
      o[4] = (short)f2bf(av[p][2*h+1].x); o[5] = (short)f2bf(av[p][2*h+1].y);
      o[6] = (short)f2bf(av[p][2*h+1].z); o[7] = (short)f2bf(av[p][2*h+1].w);
      *reinterpret_cast<short8*>(As + row * BK + (ac ^ ((row & 7) << 3))) = o;
    }
  };
  auto stageB = [&](int t, ushort* Bb) {     // 32KB: 8 waves x 4KB
    const ushort* s = Bimg + ((t * 2 + ct) * 256) * BK + wid * 2048 + lane * 8;
    ushort* d = Bb + wid * 2048;
#pragma unroll
    for (int i = 0; i < 4; ++i)
      gload_lds16(s + i * 512, d + i * 512);
  };

  floatx4 acc[4][4];
#pragma unroll
  for (int m = 0; m < 4; ++m)
#pragma unroll
    for (int n = 0; n < 4; ++n) acc[m][n] = {0.f, 0.f, 0.f, 0.f};

  auto compute = [&](const ushort* Bb) {
#pragma unroll
    for (int kh = 0; kh < 2; ++kh) {
      const int kb = kh * 32 + lg * 8;
      short8 af[4], bf[4];
#pragma unroll
      for (int m = 0; m < 4; ++m) {
        int row = wm * 64 + m * 16 + lrow;
        af[m] = *reinterpret_cast<const short8*>(As + row * BK + (kb ^ ((row & 7) << 3)));
      }
#pragma unroll
      for (int n = 0; n < 4; ++n) {
        int col = wn * 64 + n * 16 + lrow;
        bf[n] = *reinterpret_cast<const short8*>(Bb + col * BK + (kb ^ ((col & 7) << 3)));
      }
#pragma unroll
      for (int m = 0; m < 4; ++m)
#pragma unroll
        for (int n = 0; n < 4; ++n)
          acc[m][n] = __builtin_amdgcn_mfma_f32_16x16x32_bf16(af[m], bf[n], acc[m][n], 0, 0, 0);
    }
  };

  // ---- prologue: queue = [A0(4), B0(4), A1(4)] ----
  issueA(0, 0);
  stageB(0, Bs[0]);
  issueA(1, 1);
  writeA(0);               // compiler waits vmcnt(8): drains A0, leaves B0+A1
  VMCNT4;                  // drains B0, leaves A1
  LGKM0; SBAR;

  // ---- steady steps t=0..5: queue in = [A(t+1)] ----
#define STEP_MAIN(T)                                        \
  {                                                         \
    stageB((T) + 1, Bs[((T) & 1) ^ 1]);                     \
    issueA((T) + 2, (T) & 1);                               \
    compute(Bs[(T) & 1]);                                   \
    SBAR;                  /* all waves done reading As */  \
    writeA(((T) + 1) & 1); /* auto vmcnt(8): drains A(t+1) */\
    VMCNT4;                /* drains B(t+1), leaves A(t+2) */\
    LGKM0; SBAR;                                            \
  }
  STEP_MAIN(0) STEP_MAIN(1) STEP_MAIN(2)
  STEP_MAIN(3) STEP_MAIN(4) STEP_MAIN(5)
#undef STEP_MAIN

  // t = 6: stage B(7), no A(8)
  {
    stageB(7, Bs[1]);
    compute(Bs[0]);
    SBAR;
    writeA(1);             // auto vmcnt(4): drains A(7)
    VMCNT0;                // drains B(7)
    LGKM0; SBAR;
  }
  // t = 7: compute only
  compute(Bs[1]);

  // ---- epilogue: 128x256 fp32 tile, 64B-sector-aligned scalar stores ----
  float* Ob = Out + row0 * OUT_F + ct * BNB;
  const float* bb = bias + ct * BNB;
#pragma unroll
  for (int n = 0; n < 4; ++n) {
    int col = wn * 64 + n * 16 + lrow;
    float bv = bb[col];
#pragma unroll
    for (int m = 0; m < 4; ++m) {
      int rbase = wm * 64 + m * 16 + lg * 4;
#pragma unroll
      for (int j = 0; j < 4; ++j)
        Ob[(size_t)(rbase + j) * OUT_F + col] = acc[m][n][j] + bv;
    }
  }
}

extern "C" void kernel_launch(void* const* d_in, const int* in_sizes, int n_in,
                              void* d_out, int out_size, void* d_ws, size_t ws_size,
                              hipStream_t stream) {
  const float* x    = (const float*)d_in[0];
  const float* wr   = (const float*)d_in[1];
  const float* wi   = (const float*)d_in[2];
  const float* wj   = (const float*)d_in[3];
  const float* wk   = (const float*)d_in[4];
  const float* bias = (const float*)d_in[5];
  float* out = (float*)d_out;
  ushort* Bimg = (ushort*)d_ws;         // 512 KB

  int M = in_sizes[0] / KDIM;           // 131072
  int nwg = (M / BM) * 2;               // 2048

  hipLaunchKernelGGL(quat_prep_kernel, dim3((512 * 512 + 255) / 256), dim3(256), 0, stream,
                     wr, wi, wj, wk, Bimg);
  hipLaunchKernelGGL(quat_gemm_kernel, dim3(nwg), dim3(NTHREADS), 0, stream,
                     x, Bimg, bias, out);
}

// Round 12
// 174.421 us; speedup vs baseline: 1.2782x; 1.2782x over previous
//
#include <hip/hip_runtime.h>
#include <hip/hip_bf16.h>
#include <stdint.h>

#define KDIM 512
#define OUT_F 512
#define NTHREADS 512     // 8 waves x 16 rows = 128 rows per mtile

typedef __attribute__((ext_vector_type(8))) short short8;
typedef __attribute__((ext_vector_type(4))) float floatx4;

__device__ __forceinline__ ushort f2bf(float f) {
  uint32_t u = __builtin_bit_cast(uint32_t, f);
  uint32_t r = u + 0x7fffu + ((u >> 16) & 1u);   // RNE bf16
  return (ushort)(r >> 16);
}

typedef const __attribute__((address_space(1))) uint32_t* gas1_u32;
typedef __attribute__((address_space(3))) uint32_t* gas3_u32;

__device__ __forceinline__ void gload_lds16(const void* g, void* l) {
  __builtin_amdgcn_global_load_lds((gas1_u32)g, (gas3_u32)l, 16, 0, 0);
}

// ---------------------------------------------------------------------------
// Prep: W_eff (512x512) bf16 as [cs(4)][kt(8)][col(128)][k(64)], XOR swizzle
// baked in (G21: linear gload_lds dest, source perm == read perm).
// ---------------------------------------------------------------------------
__global__ void quat_prep_kernel(const float* __restrict__ wr, const float* __restrict__ wi,
                                 const float* __restrict__ wj, const float* __restrict__ wk,
                                 ushort* __restrict__ Bimg) {
  int idx = blockIdx.x * 256 + threadIdx.x;
  if (idx >= 512 * 512) return;
  int o = idx >> 9;        // output-feature index [0,512)
  int c = idx & 511;       // input-feature index [0,512)
  int og = o >> 7, oo = o & 127, cg = c >> 7, cc = c & 127;
  static const int   blkT[16] = {0,1,2,3, 1,0,3,2, 2,3,0,1, 3,2,1,0};
  static const float sgnT[16] = {1.f,-1.f,-1.f,-1.f, 1.f,1.f,1.f,-1.f,
                                 1.f,-1.f,1.f,1.f,   1.f,1.f,-1.f,1.f};
  int sel = og * 4 + cg;
  const float* Ws;
  switch (blkT[sel]) {
    case 0: Ws = wr; break;
    case 1: Ws = wi; break;
    case 2: Ws = wj; break;
    default: Ws = wk; break;
  }
  float v = sgnT[sel] * Ws[oo * 128 + cc];
  int cs = o >> 7, col = o & 127;
  int kt = c >> 6, k = c & 63;
  int dst = ((cs * 8 + kt) * 128 + col) * 64 + (k ^ ((col & 7) << 3));
  Bimg[dst] = f2bf(v);
}

// ---------------------------------------------------------------------------
// GEMM: out[M,512] = X[M,512] * W_eff^T (+bias)
// Persistent col-slab block: 128 cols x 512 rows (4 mtiles). Whole B slab
// (8 kt x 128 col x 64 k bf16 = 128 KB) in LDS, staged ONCE -> B traffic
// 128 MB total. Free-running waves (one barrier in the whole kernel):
// per-wave private A dbuf (bf16, 2KB x2), 3-deep register A prefetch
// (2-step lookahead), compiler-managed counted vmcnt. 160 KB LDS, 8 waves.
// ---------------------------------------------------------------------------
__global__ void __launch_bounds__(NTHREADS, 2)
quat_gemm_kernel(const float* __restrict__ X, const ushort* __restrict__ Bimg,
                 const float* __restrict__ bias, float* __restrict__ Out) {
  __shared__ __align__(16) ushort Bs[8 * 128 * 64];      // 128 KB
  __shared__ __align__(16) ushort As[8][2][16 * 64];     // 32 KB (per-wave dbuf)

  // 1024 blocks = 256 row-groups x 4 col-slabs; 4 cs-siblings on one XCD
  const int bid = blockIdx.x;
  const int wgid = (bid & 7) * 128 + (bid >> 3);
  const int rg = wgid >> 2;             // row-group [0,256)
  const int cs = wgid & 3;              // col-slab  [0,4)
  const size_t row0 = (size_t)rg * 512;

  const int tid = threadIdx.x, lane = tid & 63, w = tid >> 6;
  const int lrow = lane & 15;
  const int lg   = lane >> 4;

  // ---- stage whole B slab: 16 KB per wave = 16 gload_lds16 ----
  {
    const ushort* s = Bimg + cs * 65536 + w * 8192 + lane * 8;
    ushort* d = Bs + w * 8192;
#pragma unroll
    for (int i = 0; i < 16; ++i)
      gload_lds16(s + i * 512, d + i * 512);
  }

  // ---- A addressing: wave w owns rows row0 + mtile*128 + w*16 + [0,16) ----
  const float* Xw = X + (row0 + w * 16) * KDIM;
  int rlo[4];
#pragma unroll
  for (int i = 0; i < 4; ++i)
    rlo[i] = (4 * i + lg) * KDIM + lrow * 4;   // row 4i+lg, f32 cols lrow*4..+4

  float4 av[3][4];                      // 3-deep prefetch (2-step lookahead)

  auto issueA = [&](int t, int p) {     // 4 instrs x (4 rows x 256B) coalesced
    const float* base = Xw + (t >> 3) * (128 * KDIM) + (t & 7) * 64;
#pragma unroll
    for (int i = 0; i < 4; ++i)
      av[p][i] = *reinterpret_cast<const float4*>(base + rlo[i]);
  };
  auto writeA = [&](int p, int buf) {   // cvt + swizzled ds_write (private)
#pragma unroll
    for (int i = 0; i < 4; ++i) {
      int row = 4 * i + lg;
      ushort4 o4;
      o4.x = f2bf(av[p][i].x); o4.y = f2bf(av[p][i].y);
      o4.z = f2bf(av[p][i].z); o4.w = f2bf(av[p][i].w);
      *reinterpret_cast<ushort4*>(
          &As[w][buf][row * 64 + ((lrow * 4) ^ ((row & 7) << 3))]) = o4;
    }
  };

  float bv[8];
#pragma unroll
  for (int n = 0; n < 8; ++n) bv[n] = bias[cs * 128 + n * 16 + lrow];

  floatx4 acc[8];
#pragma unroll
  for (int n = 0; n < 8; ++n) acc[n] = {bv[n], bv[n], bv[n], bv[n]};

  // ---- prologue: B first in FIFO, then A0, A1. writeA(0)'s auto-wait
  // retires B+A0 (in-order vmcnt); __syncthreads publishes B once. ----
  issueA(0, 0);
  issueA(1, 1);
  writeA(0, 0);
  __syncthreads();                      // the only barrier

  const int swz = (lrow & 7) << 3;

#pragma unroll
  for (int t = 0; t < 32; ++t) {
    if (t <= 29) issueA(t + 2, (t + 2) % 3);
    if (t <= 30) writeA((t + 1) % 3, (t + 1) & 1);  // auto vmcnt leaves A(t+2)

    // compute step t: kt = t&7, reads private As buf t&1 + shared Bs
    {
      const int kt = t & 7;
      const ushort* Ab = &As[w][t & 1][0];
      const ushort* Bt = Bs + kt * (128 * 64);
#pragma unroll
      for (int kh = 0; kh < 2; ++kh) {
        const int ko = (kh * 32 + lg * 8) ^ swz;
        short8 af = *reinterpret_cast<const short8*>(Ab + lrow * 64 + ko);
#pragma unroll
        for (int n = 0; n < 8; ++n) {
          short8 bf = *reinterpret_cast<const short8*>(
              Bt + (n * 16 + lrow) * 64 + ko);
          acc[n] = __builtin_amdgcn_mfma_f32_16x16x32_bf16(af, bf, acc[n], 0, 0, 0);
        }
      }
    }

    if ((t & 7) == 7) {                 // mtile done: store 16x128, re-init acc
      const int mtile = t >> 3;
      float* Ob = Out + (row0 + mtile * 128 + w * 16) * OUT_F + cs * 128;
#pragma unroll
      for (int j = 0; j < 4; ++j) {     // j-outer, n-inner: 64B halves adjacent
        int r = lg * 4 + j;
#pragma unroll
        for (int n = 0; n < 8; ++n)
          Ob[(size_t)r * OUT_F + n * 16 + lrow] = acc[n][j];
      }
      if (t != 31) {
#pragma unroll
        for (int n = 0; n < 8; ++n) acc[n] = {bv[n], bv[n], bv[n], bv[n]};
      }
    }
  }
}

extern "C" void kernel_launch(void* const* d_in, const int* in_sizes, int n_in,
                              void* d_out, int out_size, void* d_ws, size_t ws_size,
                              hipStream_t stream) {
  const float* x    = (const float*)d_in[0];
  const float* wr   = (const float*)d_in[1];
  const float* wi   = (const float*)d_in[2];
  const float* wj   = (const float*)d_in[3];
  const float* wk   = (const float*)d_in[4];
  const float* bias = (const float*)d_in[5];
  float* out = (float*)d_out;
  ushort* Bimg = (ushort*)d_ws;         // 512 KB

  int M = in_sizes[0] / KDIM;           // 131072
  int nwg = (M / 512) * 4;              // 1024 persistent blocks

  hipLaunchKernelGGL(quat_prep_kernel, dim3((512 * 512 + 255) / 256), dim3(256), 0, stream,
                     wr, wi, wj, wk, Bimg);
  hipLaunchKernelGGL(quat_gemm_kernel, dim3(nwg), dim3(NTHREADS), 0, stream,
                     x, Bimg, bias, out);
}